// Round 5
// baseline (245.172 us; speedup 1.0000x reference)
//
#include <hip/hip_runtime.h>
#include <stdint.h>

// ---------------- problem constants ----------------
#define BB 4
#define RR 4
#define NN 4096
#define MM 64
#define KK 3
#define KNN 12288           // KK*NN
#define BRR 16              // BB*RR
#define FF 512

// canonical bf16 weight arena offsets (elements)
#define W_FPW1 0
#define W_FPW2 4096
#define W_FPW3 12288
#define W_GPW0 28928
#define W_GPW1 62208
#define W_GPW2 127744
#define W_GPW3 258816
#define W_FPB1 587520
#define W_FPB2 587584
#define W_FPB3 587712
#define W_GPB0 587840
#define W_GPB1 588096
#define W_GPB2 588352
#define W_GPB3 588864
#define W_FPB0 589376
#define W_FPW0 589440
#define W_TOT  589568

typedef short bf16x8 __attribute__((ext_vector_type(8)));
typedef float f32x4 __attribute__((ext_vector_type(4)));

__device__ __forceinline__ float bf2f(unsigned int u) {
  union { unsigned int i; float f; } v; v.i = u << 16; return v.f;
}
__device__ __forceinline__ unsigned short f2bf(float f) {
  union { float f; unsigned int i; } v; v.f = f;
  unsigned int x = v.i;
  return (unsigned short)((x + 0x7fffu + ((x >> 16) & 1u)) >> 16);
}
__device__ __forceinline__ unsigned int f2bf2(float a, float b) {
#if __has_builtin(__builtin_amdgcn_cvt_pk_bf16_f32)
  typedef __bf16 bf2_t __attribute__((ext_vector_type(2)));
  union { bf2_t v; unsigned int u; } c;
  c.v = __builtin_amdgcn_cvt_pk_bf16_f32(a, b);
  return c.u;
#else
  return (unsigned int)f2bf(a) | ((unsigned int)f2bf(b) << 16);
#endif
}
// dtype-adaptive load: isbf=1 -> bf16 ushorts; else fp32 floats
__device__ __forceinline__ float ldf(const void* p, long i, int isbf) {
  if (isbf) return bf2f(((const unsigned short*)p)[i]);
  return ((const float*)p)[i];
}
// per-block dtype probe: sample 64 even-index ushorts of x, vote on exponents
__device__ __forceinline__ int detect_bf(const unsigned short* xs) {
  int lane = threadIdx.x & 63;
  unsigned short u = xs[lane * 2];
  int e = (u >> 7) & 0xFF;
  int bad = (e >= 0x90 || (e > 0 && e <= 0x50)) ? 1 : 0;
  unsigned long long m = __ballot(bad);
  return __popcll(m) < 16;
}

// ---------------- K1: weight canonicalize (blocks >=64) + assign (blocks 0..63) ----
struct SrcPtrs { const void* p[16]; };
__global__ __launch_bounds__(256) void k_pre(
    SrcPtrs sp, const void* __restrict__ x, const void* __restrict__ node,
    int* __restrict__ idx, float* __restrict__ csum, int* __restrict__ blkcnt,
    unsigned short* __restrict__ Wb) {
  int isbf = detect_bf((const unsigned short*)x);
  int tid = threadIdx.x;
  if (blockIdx.x >= 64) {
    // ---- cvt part ----
    int t = (blockIdx.x - 64) * 256 + tid;
    if (t >= W_TOT) return;
    int s, base;
    if (t < 28928) {
      if (t < 4096)        { s=0;  base=0; }
      else if (t < 12288)  { s=1;  base=4096; }
      else                 { s=2;  base=12288; }
    } else if (t < 587520) {
      if (t < 62208)       { s=3;  base=28928; }
      else if (t < 127744) { s=4;  base=62208; }
      else if (t < 258816) { s=5;  base=127744; }
      else                 { s=6;  base=258816; }
    } else if (t < 588864) {
      if (t < 587584)      { s=7;  base=587520; }
      else if (t < 587712) { s=8;  base=587584; }
      else if (t < 587840) { s=9;  base=587712; }
      else if (t < 588096) { s=10; base=587840; }
      else if (t < 588352) { s=11; base=588096; }
      else                 { s=12; base=588352; }
    } else {
      if (t < 589376)      { s=13; base=588864; }
      else if (t < 589440) { s=14; base=589376; }
      else                 { s=15; base=589440; }
    }
    int local = t - base;
    Wb[t] = isbf ? ((const unsigned short*)sp.p[s])[local]
                 : f2bf(((const float*)sp.p[s])[local]);
    return;
  }
  // ---- assign part: top-3 + cluster sums + per-chunk histogram ----
  __shared__ float nd[2][64];
  __shared__ float cs[192];   // [m][{sx,sy,cnt}]
  int b = blockIdx.x >> 4;
  int n = ((blockIdx.x & 15) << 8) + tid;
  if (tid < 128) nd[tid >> 6][tid & 63] = ldf(node, b * 128 + tid, isbf);
  if (tid < 192) cs[tid] = 0.f;
  __syncthreads();
  float x0 = ldf(x, b * 8192 + n, isbf);
  float x1 = ldf(x, b * 8192 + 4096 + n, isbf);
  float d0 = 1e30f, d1 = 1e30f, d2 = 1e30f;
  int m0 = 0, m1 = 0, m2 = 0;
#pragma unroll 8
  for (int m = 0; m < 64; ++m) {
    float dx = x0 - nd[0][m];
    float dy = x1 - nd[1][m];
    float d = __fmul_rn(dx, dx) + __fmul_rn(dy, dy);   // no contraction: match ref
    if (d < d0)      { d2=d1; m2=m1; d1=d0; m1=m0; d0=d; m0=m; }
    else if (d < d1) { d2=d1; m2=m1; d1=d;  m1=m; }
    else if (d < d2) { d2=d;  m2=m; }
  }
  long base = ((long)b * NN + n) * 3;
  idx[base] = m0; idx[base + 1] = m1; idx[base + 2] = m2;
  atomicAdd(&cs[m0*3+0], x0); atomicAdd(&cs[m0*3+1], x1); atomicAdd(&cs[m0*3+2], 1.f);
  atomicAdd(&cs[m1*3+0], x0); atomicAdd(&cs[m1*3+1], x1); atomicAdd(&cs[m1*3+2], 1.f);
  atomicAdd(&cs[m2*3+0], x0); atomicAdd(&cs[m2*3+1], x1); atomicAdd(&cs[m2*3+2], 1.f);
  __syncthreads();
  if (tid < 192) atomicAdd(&csum[b * 192 + tid], cs[tid]);
  if (tid < 64) blkcnt[blockIdx.x * 64 + tid] = (int)cs[tid*3 + 2];
}

// ---------------- K2: merged means + prefix + counting-sort scatter ----------------
__global__ __launch_bounds__(256) void k_mid(
    const float* __restrict__ csum, const int* __restrict__ blkcnt,
    const int* __restrict__ idx,
    float* __restrict__ noderot, int* __restrict__ rowflag,
    int* __restrict__ sorted) {
  __shared__ float cls[192];
  __shared__ int offs[64];
  __shared__ int lbase[64];
  __shared__ int lc[64];
  int tid = threadIdx.x;
  int blk = blockIdx.x;           // b*16 + chunk
  int b = blk >> 4, chunk = blk & 15;
  if (tid < 192) cls[tid] = csum[b * 192 + tid];
  __syncthreads();
  if (tid < 64) {
    int m = tid;
    float s0 = cls[m*3], s1 = cls[m*3+1], c = cls[m*3+2];
    float mx = s0 / (c + 1e-5f), my = s1 / (c + 1e-5f);
    rowflag[b*64 + m] = (c > 0.f) ? 1 : 0;         // redundant identical writes, safe
    for (int r = 0; r < 4; ++r) {
      float th = 1.5707964f * (float)r;
      float cr = cosf(th), sr = sinf(th);
      noderot[((b*4+r)*2+0)*64 + m] = cr*mx - sr*my;
      noderot[((b*4+r)*2+1)*64 + m] = sr*mx + cr*my;
    }
    lc[m] = 0;
  }
  if (tid == 0) {                 // serial prefix over 64 m (counts exact in fp32)
    int acc = 0;
    for (int mm = 0; mm < 64; ++mm) { offs[mm] = acc; acc += (int)cls[mm*3+2]; }
  }
  __syncthreads();
  if (tid < 64) {
    int base = offs[tid];
    for (int c2 = 0; c2 < chunk; ++c2) base += blkcnt[(b*16 + c2)*64 + tid];
    lbase[tid] = base;
  }
  __syncthreads();
  int n = (chunk << 8) + tid;
#pragma unroll
  for (int kk = 0; kk < 3; ++kk) {
    int m = idx[((long)b*NN + n)*3 + kk];
    int pos = atomicAdd(&lc[m], 1);               // LDS atomic, order irrelevant
    sorted[b*KNN + lbase[m] + pos] = (m << 12) | n;
  }
}

// ---------------- K3: fused fp block (xdec -> 4 layers -> run-scan segment max) ------
// grid (192, 16): 64 m-sorted columns per block, one br per blockIdx.y.
__global__ __launch_bounds__(256) void k_fused(
    const void* __restrict__ x, const int* __restrict__ sorted,
    const int* __restrict__ idx, const float* __restrict__ noderot,
    const unsigned short* __restrict__ Wb,
    unsigned int* __restrict__ pooled, float* __restrict__ feat0) {
  __shared__ unsigned short Cs[64 * 136];   // [col][0..1]=xdec,[2..129]=h2; later [0..127]=feat
  __shared__ unsigned short Hs[64 * 72];    // h1 (stride 72 -> 144B, 16B-mult)
  __shared__ int mcol[64];                  // m | (is_col0 << 8)
  const unsigned short* fW1 = Wb + W_FPW1;
  const unsigned short* fW2 = Wb + W_FPW2;
  const unsigned short* fW3 = Wb + W_FPW3;
  const unsigned short* fb1 = Wb + W_FPB1;
  const unsigned short* fb2 = Wb + W_FPB2;
  const unsigned short* fb3 = Wb + W_FPB3;
  const unsigned short* fb0 = Wb + W_FPB0;
  const unsigned short* fW0 = Wb + W_FPW0;
  int isbf = detect_bf((const unsigned short*)x);
  int tid = threadIdx.x, lane = tid & 63, wv = tid >> 6;
  int quad = lane >> 4, lr = lane & 15;
  int br = blockIdx.y, b = br >> 2, r = br & 3;
  if (tid < 64) {
    int e = sorted[b * KNN + blockIdx.x * 64 + tid];
    int m = e >> 12, n = e & 4095;
    int isz = (n == 0 && m == idx[(long)b * NN * 3]) ? 256 : 0;
    mcol[tid] = m | isz;
    float x0 = ldf(x, b*8192 + n, isbf), x1 = ldf(x, b*8192 + 4096 + n, isbf);
    float th = 1.5707964f * (float)r;
    float cr = cosf(th), sr = sinf(th);
    float xd0 = (cr*x0 - sr*x1) - noderot[(br*2 + 0)*64 + m];
    float xd1 = (sr*x0 + cr*x1) - noderot[(br*2 + 1)*64 + m];
    *(unsigned int*)&Cs[tid * 136] = f2bf2(xd0, xd1);
  }
  __syncthreads();
  // ----- layer0 (2 -> 64), VALU -----
  {
    int col = tid & 63, og = (tid >> 6) << 4;
    unsigned int xu = *(unsigned int*)&Cs[col * 136];
    float fx0 = bf2f(xu & 0xffff), fx1 = bf2f(xu >> 16);
    union { unsigned int u[8]; bf16x8 v[2]; } o8;
#pragma unroll
    for (int j = 0; j < 16; j += 2) {
      int o = og + j;
      unsigned int wu0 = *(const unsigned int*)&fW0[o*2];
      unsigned int wu1 = *(const unsigned int*)&fW0[o*2 + 2];
      float h0 = bf2f(fb0[o])   + bf2f(wu0 & 0xffff)*fx0 + bf2f(wu0 >> 16)*fx1;
      float h1 = bf2f(fb0[o+1]) + bf2f(wu1 & 0xffff)*fx0 + bf2f(wu1 >> 16)*fx1;
      o8.u[j >> 1] = f2bf2(fmaxf(h0, 0.f), fmaxf(h1, 0.f));
    }
    *(bf16x8*)&Hs[col*72 + og]     = o8.v[0];
    *(bf16x8*)&Hs[col*72 + og + 8] = o8.v[1];
  }
  __syncthreads();
  // ----- layer1 (64 -> 64), MFMA -----
  {
    int o0 = wv * 16;
    f32x4 acc[4];
    float bb4[4];
#pragma unroll
    for (int rr = 0; rr < 4; ++rr) bb4[rr] = bf2f(fb1[o0 + quad*4 + rr]);
#pragma unroll
    for (int nt = 0; nt < 4; ++nt) acc[nt] = (f32x4){bb4[0], bb4[1], bb4[2], bb4[3]};
#pragma unroll
    for (int ks = 0; ks < 64; ks += 32) {
      bf16x8 a = *(const bf16x8*)(fW1 + (o0 + lr)*64 + ks + quad*8);
#pragma unroll
      for (int nt = 0; nt < 4; ++nt) {
        bf16x8 bf = *(bf16x8*)&Hs[(nt*16 + lr)*72 + ks + quad*8];
        acc[nt] = __builtin_amdgcn_mfma_f32_16x16x32_bf16(a, bf, acc[nt], 0, 0, 0);
      }
    }
    __syncthreads();  // everyone done READING Hs
#pragma unroll
    for (int nt = 0; nt < 4; ++nt) {
      int col = nt*16 + lr;
      unsigned long long pk =
        (unsigned long long)f2bf2(fmaxf(acc[nt][0],0.f), fmaxf(acc[nt][1],0.f)) |
        ((unsigned long long)f2bf2(fmaxf(acc[nt][2],0.f), fmaxf(acc[nt][3],0.f)) << 32);
      *(unsigned long long*)&Hs[col*72 + o0 + quad*4] = pk;
    }
  }
  __syncthreads();
  // ----- layer2 (64 -> 128), MFMA, output into Cs[2..129] -----
#pragma unroll
  for (int p2 = 0; p2 < 2; ++p2) {
    int o0 = p2*64 + wv*16;
    f32x4 acc[4];
    float bb4[4];
#pragma unroll
    for (int rr = 0; rr < 4; ++rr) bb4[rr] = bf2f(fb2[o0 + quad*4 + rr]);
#pragma unroll
    for (int nt = 0; nt < 4; ++nt) acc[nt] = (f32x4){bb4[0], bb4[1], bb4[2], bb4[3]};
#pragma unroll
    for (int ks = 0; ks < 64; ks += 32) {
      bf16x8 a = *(const bf16x8*)(fW2 + (o0 + lr)*64 + ks + quad*8);
#pragma unroll
      for (int nt = 0; nt < 4; ++nt) {
        bf16x8 bf = *(bf16x8*)&Hs[(nt*16 + lr)*72 + ks + quad*8];
        acc[nt] = __builtin_amdgcn_mfma_f32_16x16x32_bf16(a, bf, acc[nt], 0, 0, 0);
      }
    }
#pragma unroll
    for (int nt = 0; nt < 4; ++nt) {
      int col = nt*16 + lr;
      int o = o0 + quad*4;
      *(unsigned int*)&Cs[col*136 + 2 + o] = f2bf2(fmaxf(acc[nt][0],0.f), fmaxf(acc[nt][1],0.f));
      *(unsigned int*)&Cs[col*136 + 4 + o] = f2bf2(fmaxf(acc[nt][2],0.f), fmaxf(acc[nt][3],0.f));
    }
  }
  __syncthreads();
  // ----- layer3 (130 -> 128): both halves in registers, then feats -> Cs[0..127] -----
  f32x4 acc3[2][4];
#pragma unroll
  for (int p3 = 0; p3 < 2; ++p3) {
    int o0 = p3*64 + wv*16;
    float bb4[4];
#pragma unroll
    for (int rr = 0; rr < 4; ++rr) bb4[rr] = bf2f(fb3[o0 + quad*4 + rr]);
#pragma unroll
    for (int nt = 0; nt < 4; ++nt) acc3[p3][nt] = (f32x4){bb4[0], bb4[1], bb4[2], bb4[3]};
#pragma unroll
    for (int ks = 0; ks < 128; ks += 32) {
      union { bf16x8 v; unsigned int u[4]; } au;
      const unsigned int* ap = (const unsigned int*)(fW3 + (long)(o0 + lr)*130 + ks + quad*8);
      au.u[0] = ap[0]; au.u[1] = ap[1]; au.u[2] = ap[2]; au.u[3] = ap[3];
#pragma unroll
      for (int nt = 0; nt < 4; ++nt) {
        bf16x8 bf = *(bf16x8*)&Cs[(nt*16 + lr)*136 + ks + quad*8];
        acc3[p3][nt] = __builtin_amdgcn_mfma_f32_16x16x32_bf16(au.v, bf, acc3[p3][nt], 0, 0, 0);
      }
    }
#pragma unroll
    for (int rr = 0; rr < 4; ++rr) {   // K tail: channels 128..129
      int o = o0 + quad*4 + rr;
      unsigned int wu = *(const unsigned int*)(fW3 + (long)o*130 + 128);
      float w0 = bf2f(wu & 0xffff), w1 = bf2f(wu >> 16);
#pragma unroll
      for (int nt = 0; nt < 4; ++nt) {
        unsigned int bu = *(unsigned int*)&Cs[(nt*16 + lr)*136 + 128];
        acc3[p3][nt][rr] += w0 * bf2f(bu & 0xffff) + w1 * bf2f(bu >> 16);
      }
    }
  }
  __syncthreads();   // ALL Cs reads complete before feat overwrite
#pragma unroll
  for (int p3 = 0; p3 < 2; ++p3) {
    int o0 = p3*64 + wv*16;
#pragma unroll
    for (int nt = 0; nt < 4; ++nt) {
      int col = nt*16 + lr;
      unsigned long long pk =
        (unsigned long long)f2bf2(fmaxf(acc3[p3][nt][0],0.f), fmaxf(acc3[p3][nt][1],0.f)) |
        ((unsigned long long)f2bf2(fmaxf(acc3[p3][nt][2],0.f), fmaxf(acc3[p3][nt][3],0.f)) << 32);
      *(unsigned long long*)&Cs[col*136 + o0 + quad*4] = pk;
    }
  }
  __syncthreads();
  // ----- run-scan segment max: thread = (row o, col-half h); runs contiguous --------
  {
    int o = tid & 127, h = tid >> 7;
    int c0 = h * 32;
    int curm = mcol[c0] & 255;
    float v = 0.f;                       // relu'd values >= 0
    for (int c = c0; c < c0 + 32; ++c) {
      int mc = mcol[c];
      int mm = mc & 255;
      float f = bf2f(Cs[c*136 + o]);
      if (mm != curm) {
        atomicMax(&pooled[(((long)br*64 + curm) << 7) + o], __float_as_uint(v));
        curm = mm; v = 0.f;
      }
      v = fmaxf(v, f);
      if (mc & 256) feat0[br*128 + o] = f;   // (kk=0,n=0) column
    }
    atomicMax(&pooled[(((long)br*64 + curm) << 7) + o], __float_as_uint(v));
  }
}

// ---------------- K4: fused gp block (finalize -> 4 layers -> global max -> out) ------
// grid 64: 16 columns (one br, 16 m's) per block, whole gp chain in LDS.
__global__ __launch_bounds__(256) void k_gp(
    const void* __restrict__ x,
    const unsigned int* __restrict__ pooled, const float* __restrict__ feat0,
    const int* __restrict__ rowflag, const float* __restrict__ noderot,
    const unsigned short* __restrict__ Wb,
    unsigned int* __restrict__ outmax, unsigned int* __restrict__ counter,
    void* __restrict__ out) {
  __shared__ unsigned short AGs[16 * 648];  // [col][0..1]=node,[2..129]=pooled,[130..641]=h2
  __shared__ unsigned short H1s[16 * 264];
  __shared__ unsigned short H2s[16 * 264];
  __shared__ int done_s;
  int isbf = detect_bf((const unsigned short*)x);
  int tid = threadIdx.x, lane = tid & 63, wv = tid >> 6;
  int quad = lane >> 4, lr = lane & 15;
  int col0 = blockIdx.x * 16;
  int br = col0 >> 6, b = br >> 2;
  // ---- stage A: build AG tile (finalize) ----
  for (int i = tid; i < 2048; i += 256) {
    int c = i >> 7, o = i & 127;
    int gc = col0 + c, m = gc & 63;
    float v = __uint_as_float(pooled[((long)gc << 7) + o]);
    if (!rowflag[b * 64 + m]) v = feat0[br * 128 + o];
    AGs[c * 648 + 2 + o] = f2bf(v);
  }
  if (tid < 32) {
    int c = tid >> 1, j = tid & 1;
    int m = (col0 + c) & 63;
    AGs[c * 648 + j] = f2bf(noderot[(br * 2 + j) * 64 + m]);
  }
  __syncthreads();
  // ---- gp0: 256 rows, K=130 (128 MFMA + 2 tail) ----
  {
    const unsigned short* W = Wb + W_GPW0;
    const unsigned short* Bi = Wb + W_GPB0;
    f32x4 acc[4];
#pragma unroll
    for (int rt = 0; rt < 4; ++rt) {
      int o0 = wv*64 + rt*16 + quad*4;
      acc[rt] = (f32x4){bf2f(Bi[o0]), bf2f(Bi[o0+1]), bf2f(Bi[o0+2]), bf2f(Bi[o0+3])};
    }
#pragma unroll
    for (int ks = 0; ks < 128; ks += 32) {
      bf16x8 bfr = *(bf16x8*)&AGs[lr * 648 + ks + quad * 8];
#pragma unroll
      for (int rt = 0; rt < 4; ++rt) {
        int o0 = wv*64 + rt*16;
        union { bf16x8 v; unsigned int u[4]; } au;
        const unsigned int* ap = (const unsigned int*)(W + (o0 + lr)*130 + ks + quad*8);
        au.u[0]=ap[0]; au.u[1]=ap[1]; au.u[2]=ap[2]; au.u[3]=ap[3];
        acc[rt] = __builtin_amdgcn_mfma_f32_16x16x32_bf16(au.v, bfr, acc[rt], 0,0,0);
      }
    }
    unsigned int bu = *(unsigned int*)&AGs[lr * 648 + 128];
    float b0v = bf2f(bu & 0xffff), b1v = bf2f(bu >> 16);
#pragma unroll
    for (int rt = 0; rt < 4; ++rt) {
#pragma unroll
      for (int rr = 0; rr < 4; ++rr) {
        int o = wv*64 + rt*16 + quad*4 + rr;
        unsigned int wu = *(const unsigned int*)(W + o*130 + 128);
        acc[rt][rr] += bf2f(wu & 0xffff)*b0v + bf2f(wu >> 16)*b1v;
      }
      int o0 = wv*64 + rt*16;
      unsigned long long pk =
        (unsigned long long)f2bf2(fmaxf(acc[rt][0],0.f), fmaxf(acc[rt][1],0.f)) |
        ((unsigned long long)f2bf2(fmaxf(acc[rt][2],0.f), fmaxf(acc[rt][3],0.f)) << 32);
      *(unsigned long long*)&H1s[lr*264 + o0 + quad*4] = pk;
    }
  }
  __syncthreads();
  // ---- gp1: 256 rows, K=256 ----
  {
    const unsigned short* W = Wb + W_GPW1;
    const unsigned short* Bi = Wb + W_GPB1;
    f32x4 acc[4];
#pragma unroll
    for (int rt = 0; rt < 4; ++rt) {
      int o0 = wv*64 + rt*16 + quad*4;
      acc[rt] = (f32x4){bf2f(Bi[o0]), bf2f(Bi[o0+1]), bf2f(Bi[o0+2]), bf2f(Bi[o0+3])};
    }
    for (int ks = 0; ks < 256; ks += 32) {
      bf16x8 bfr = *(bf16x8*)&H1s[lr * 264 + ks + quad * 8];
#pragma unroll
      for (int rt = 0; rt < 4; ++rt) {
        int o0 = wv*64 + rt*16;
        bf16x8 a = *(const bf16x8*)(W + (o0 + lr)*256 + ks + quad*8);
        acc[rt] = __builtin_amdgcn_mfma_f32_16x16x32_bf16(a, bfr, acc[rt], 0,0,0);
      }
    }
#pragma unroll
    for (int rt = 0; rt < 4; ++rt) {
      int o0 = wv*64 + rt*16;
      unsigned long long pk =
        (unsigned long long)f2bf2(fmaxf(acc[rt][0],0.f), fmaxf(acc[rt][1],0.f)) |
        ((unsigned long long)f2bf2(fmaxf(acc[rt][2],0.f), fmaxf(acc[rt][3],0.f)) << 32);
      *(unsigned long long*)&H2s[lr*264 + o0 + quad*4] = pk;
    }
  }
  __syncthreads();
  // ---- gp2: 512 rows, K=256, out -> AGs[130..641] ----
  {
    const unsigned short* W = Wb + W_GPW2;
    const unsigned short* Bi = Wb + W_GPB2;
    f32x4 acc[8];
#pragma unroll
    for (int rt = 0; rt < 8; ++rt) {
      int o0 = wv*128 + rt*16 + quad*4;
      acc[rt] = (f32x4){bf2f(Bi[o0]), bf2f(Bi[o0+1]), bf2f(Bi[o0+2]), bf2f(Bi[o0+3])};
    }
    for (int ks = 0; ks < 256; ks += 32) {
      bf16x8 bfr = *(bf16x8*)&H2s[lr * 264 + ks + quad * 8];
#pragma unroll
      for (int rt = 0; rt < 8; ++rt) {
        int o0 = wv*128 + rt*16;
        bf16x8 a = *(const bf16x8*)(W + (o0 + lr)*256 + ks + quad*8);
        acc[rt] = __builtin_amdgcn_mfma_f32_16x16x32_bf16(a, bfr, acc[rt], 0,0,0);
      }
    }
#pragma unroll
    for (int rt = 0; rt < 8; ++rt) {
      int o0 = wv*128 + rt*16;
      *(unsigned int*)&AGs[lr*648 + 130 + o0 + quad*4] =
          f2bf2(fmaxf(acc[rt][0],0.f), fmaxf(acc[rt][1],0.f));
      *(unsigned int*)&AGs[lr*648 + 132 + o0 + quad*4] =
          f2bf2(fmaxf(acc[rt][2],0.f), fmaxf(acc[rt][3],0.f));
    }
  }
  __syncthreads();
  // ---- gp3: 512 rows, K=642 (640 MFMA + 2 tail), relu + max over cols -> outmax ----
  {
    const unsigned short* W = Wb + W_GPW3;
    const unsigned short* Bi = Wb + W_GPB3;
    f32x4 acc[8];
#pragma unroll
    for (int rt = 0; rt < 8; ++rt) {
      int o0 = wv*128 + rt*16 + quad*4;
      acc[rt] = (f32x4){bf2f(Bi[o0]), bf2f(Bi[o0+1]), bf2f(Bi[o0+2]), bf2f(Bi[o0+3])};
    }
    for (int ks = 0; ks < 640; ks += 32) {
      bf16x8 bfr = *(bf16x8*)&AGs[lr * 648 + ks + quad * 8];
#pragma unroll
      for (int rt = 0; rt < 8; ++rt) {
        int o0 = wv*128 + rt*16;
        union { bf16x8 v; unsigned int u[4]; } au;
        const unsigned int* ap = (const unsigned int*)(W + (long)(o0 + lr)*642 + ks + quad*8);
        au.u[0]=ap[0]; au.u[1]=ap[1]; au.u[2]=ap[2]; au.u[3]=ap[3];
        acc[rt] = __builtin_amdgcn_mfma_f32_16x16x32_bf16(au.v, bfr, acc[rt], 0,0,0);
      }
    }
    unsigned int bu = *(unsigned int*)&AGs[lr * 648 + 640];
    float b0v = bf2f(bu & 0xffff), b1v = bf2f(bu >> 16);
#pragma unroll
    for (int rt = 0; rt < 8; ++rt) {
#pragma unroll
      for (int rr = 0; rr < 4; ++rr) {
        int o = wv*128 + rt*16 + quad*4 + rr;
        unsigned int wu = *(const unsigned int*)(W + (long)o*642 + 640);
        float v = acc[rt][rr] + bf2f(wu & 0xffff)*b0v + bf2f(wu >> 16)*b1v;
        v = fmaxf(v, 0.f);
        v = fmaxf(v, __shfl_xor(v, 1, 64));
        v = fmaxf(v, __shfl_xor(v, 2, 64));
        v = fmaxf(v, __shfl_xor(v, 4, 64));
        v = fmaxf(v, __shfl_xor(v, 8, 64));
        if (lr == 0) atomicMax(&outmax[b * FF + o], __float_as_uint(v));
      }
    }
  }
  // ---- last block converts outmax -> out ----
  __threadfence();
  __syncthreads();
  if (tid == 0) done_s = (int)atomicAdd(counter, 1u);
  __syncthreads();
  if (done_s == 63) {
    for (int t = tid; t < 2048; t += 256) {
      float v = __uint_as_float(atomicMax(&outmax[t], 0u));  // coherent device-scope read
      if (isbf) ((unsigned short*)out)[t] = f2bf(v);
      else      ((float*)out)[t] = v;
    }
  }
}

// ---------------- host ----------------
extern "C" void kernel_launch(void* const* d_in, const int* in_sizes, int n_in,
                              void* d_out, int out_size, void* d_ws, size_t ws_size,
                              hipStream_t stream) {
  const void* x    = d_in[0];
  const void* node = d_in[2];

  char* ws = (char*)d_ws;
  float*          csum    = (float*)(ws + 0);              //   3072
  unsigned int*   outmax  = (unsigned int*)(ws + 3072);    //   8192
  unsigned int*   counter = (unsigned int*)(ws + 11264);   //    256
  unsigned int*   pooled  = (unsigned int*)(ws + 11520);   // 524288
  // ---- end of memset region (535808 B) ----
  int*            idx     = (int*)(ws + 535808);           // 196608
  int*            blkcnt  = (int*)(ws + 732416);           //  16384
  float*          noderot = (float*)(ws + 748800);         //   8192
  int*            rowflag = (int*)(ws + 756992);           //   1024
  int*            sorted  = (int*)(ws + 758016);           // 196608
  float*          feat0   = (float*)(ws + 954624);         //   8192
  unsigned short* Wb      = (unsigned short*)(ws + 962816);// 1179136 -> end 2141952

  hipMemsetAsync(ws, 0, 535808, stream);

  SrcPtrs sp;
  sp.p[0]  = d_in[6];   // fpW1
  sp.p[1]  = d_in[8];   // fpW2
  sp.p[2]  = d_in[10];  // fpW3
  sp.p[3]  = d_in[12];  // gpW0
  sp.p[4]  = d_in[14];  // gpW1
  sp.p[5]  = d_in[16];  // gpW2
  sp.p[6]  = d_in[18];  // gpW3
  sp.p[7]  = d_in[7];   // fpb1
  sp.p[8]  = d_in[9];   // fpb2
  sp.p[9]  = d_in[11];  // fpb3
  sp.p[10] = d_in[13];  // gpb0
  sp.p[11] = d_in[15];  // gpb1
  sp.p[12] = d_in[17];  // gpb2
  sp.p[13] = d_in[19];  // gpb3
  sp.p[14] = d_in[5];   // fpb0
  sp.p[15] = d_in[4];   // fpW0

  k_pre<<<64 + (W_TOT + 255) / 256, 256, 0, stream>>>(sp, x, node, idx, csum, blkcnt, Wb);
  k_mid<<<64, 256, 0, stream>>>(csum, blkcnt, idx, noderot, rowflag, sorted);
  k_fused<<<dim3(192, 16), 256, 0, stream>>>(x, sorted, idx, noderot, Wb, pooled, feat0);
  k_gp<<<64, 256, 0, stream>>>(x, pooled, feat0, rowflag, noderot, Wb,
                               outmax, counter, d_out);
}

// Round 6
// 205.835 us; speedup vs baseline: 1.1911x; 1.1911x over previous
//
#include <hip/hip_runtime.h>
#include <stdint.h>

// ---------------- problem constants ----------------
#define BB 4
#define RR 4
#define NN 4096
#define MM 64
#define KK 3
#define KNN 12288           // KK*NN
#define BRR 16              // BB*RR
#define FF 512

// canonical bf16 weight arena offsets (elements)
#define W_FPW1 0
#define W_FPW2 4096
#define W_FPW3 12288
#define W_GPW0 28928
#define W_GPW1 62208
#define W_GPW2 127744
#define W_GPW3 258816
#define W_FPB1 587520
#define W_FPB2 587584
#define W_FPB3 587712
#define W_GPB0 587840
#define W_GPB1 588096
#define W_GPB2 588352
#define W_GPB3 588864
#define W_FPB0 589376
#define W_FPW0 589440
#define W_TOT  589568

typedef short bf16x8 __attribute__((ext_vector_type(8)));
typedef float f32x4 __attribute__((ext_vector_type(4)));

__device__ __forceinline__ float bf2f(unsigned int u) {
  union { unsigned int i; float f; } v; v.i = u << 16; return v.f;
}
__device__ __forceinline__ unsigned short f2bf(float f) {
  union { float f; unsigned int i; } v; v.f = f;
  unsigned int x = v.i;
  return (unsigned short)((x + 0x7fffu + ((x >> 16) & 1u)) >> 16);
}
__device__ __forceinline__ unsigned int f2bf2(float a, float b) {
#if __has_builtin(__builtin_amdgcn_cvt_pk_bf16_f32)
  typedef __bf16 bf2_t __attribute__((ext_vector_type(2)));
  union { bf2_t v; unsigned int u; } c;
  c.v = __builtin_amdgcn_cvt_pk_bf16_f32(a, b);
  return c.u;
#else
  return (unsigned int)f2bf(a) | ((unsigned int)f2bf(b) << 16);
#endif
}
// dtype-adaptive load: isbf=1 -> bf16 ushorts; else fp32 floats
__device__ __forceinline__ float ldf(const void* p, long i, int isbf) {
  if (isbf) return bf2f(((const unsigned short*)p)[i]);
  return ((const float*)p)[i];
}
// per-wave dtype probe: sample 64 even-index ushorts of x, vote on exponents
__device__ __forceinline__ int detect_bf(const unsigned short* xs) {
  int lane = threadIdx.x & 63;
  unsigned short u = xs[lane * 2];
  int e = (u >> 7) & 0xFF;
  int bad = (e >= 0x90 || (e > 0 && e <= 0x50)) ? 1 : 0;
  unsigned long long m = __ballot(bad);
  return __popcll(m) < 16;
}

// ---------------- K1: weight canonicalize (blocks >=64) + assign (blocks 0..63) ----
struct SrcPtrs { const void* p[16]; };
__global__ __launch_bounds__(256) void k_pre(
    SrcPtrs sp, const void* __restrict__ x, const void* __restrict__ node,
    int* __restrict__ idx, float* __restrict__ csum, int* __restrict__ blkcnt,
    unsigned short* __restrict__ Wb) {
  int isbf = detect_bf((const unsigned short*)x);
  int tid = threadIdx.x;
  if (blockIdx.x >= 64) {
    // ---- cvt part ----
    int t = (blockIdx.x - 64) * 256 + tid;
    if (t >= W_TOT) return;
    int s, base;
    if (t < 28928) {
      if (t < 4096)        { s=0;  base=0; }
      else if (t < 12288)  { s=1;  base=4096; }
      else                 { s=2;  base=12288; }
    } else if (t < 587520) {
      if (t < 62208)       { s=3;  base=28928; }
      else if (t < 127744) { s=4;  base=62208; }
      else if (t < 258816) { s=5;  base=127744; }
      else                 { s=6;  base=258816; }
    } else if (t < 588864) {
      if (t < 587584)      { s=7;  base=587520; }
      else if (t < 587712) { s=8;  base=587584; }
      else if (t < 587840) { s=9;  base=587712; }
      else if (t < 588096) { s=10; base=587840; }
      else if (t < 588352) { s=11; base=588096; }
      else                 { s=12; base=588352; }
    } else {
      if (t < 589376)      { s=13; base=588864; }
      else if (t < 589440) { s=14; base=589376; }
      else                 { s=15; base=589440; }
    }
    int local = t - base;
    Wb[t] = isbf ? ((const unsigned short*)sp.p[s])[local]
                 : f2bf(((const float*)sp.p[s])[local]);
    return;
  }
  // ---- assign part: top-3 + cluster sums + per-chunk histogram ----
  __shared__ float nd[2][64];
  __shared__ float cs[192];   // [m][{sx,sy,cnt}]
  int b = blockIdx.x >> 4;
  int n = ((blockIdx.x & 15) << 8) + tid;
  if (tid < 128) nd[tid >> 6][tid & 63] = ldf(node, b * 128 + tid, isbf);
  if (tid < 192) cs[tid] = 0.f;
  __syncthreads();
  float x0 = ldf(x, b * 8192 + n, isbf);
  float x1 = ldf(x, b * 8192 + 4096 + n, isbf);
  float d0 = 1e30f, d1 = 1e30f, d2 = 1e30f;
  int m0 = 0, m1 = 0, m2 = 0;
#pragma unroll 8
  for (int m = 0; m < 64; ++m) {
    float dx = x0 - nd[0][m];
    float dy = x1 - nd[1][m];
    float d = __fmul_rn(dx, dx) + __fmul_rn(dy, dy);   // no contraction: match ref
    if (d < d0)      { d2=d1; m2=m1; d1=d0; m1=m0; d0=d; m0=m; }
    else if (d < d1) { d2=d1; m2=m1; d1=d;  m1=m; }
    else if (d < d2) { d2=d;  m2=m; }
  }
  long base = ((long)b * NN + n) * 3;
  idx[base] = m0; idx[base + 1] = m1; idx[base + 2] = m2;
  atomicAdd(&cs[m0*3+0], x0); atomicAdd(&cs[m0*3+1], x1); atomicAdd(&cs[m0*3+2], 1.f);
  atomicAdd(&cs[m1*3+0], x0); atomicAdd(&cs[m1*3+1], x1); atomicAdd(&cs[m1*3+2], 1.f);
  atomicAdd(&cs[m2*3+0], x0); atomicAdd(&cs[m2*3+1], x1); atomicAdd(&cs[m2*3+2], 1.f);
  __syncthreads();
  if (tid < 192) atomicAdd(&csum[b * 192 + tid], cs[tid]);
  if (tid < 64) blkcnt[blockIdx.x * 64 + tid] = (int)cs[tid*3 + 2];
}

// ---------------- K2: merged means + prefix + counting-sort scatter + pooled init ----
__global__ __launch_bounds__(256) void k_mid(
    const float* __restrict__ csum, const int* __restrict__ blkcnt,
    const int* __restrict__ idx,
    float* __restrict__ noderot, int* __restrict__ rowflag,
    int* __restrict__ sorted, unsigned int* __restrict__ pooled) {
  __shared__ float cls[192];
  __shared__ int offs[64];
  __shared__ int lbase[64];
  __shared__ int lc[64];
  int tid = threadIdx.x;
  int blk = blockIdx.x;           // b*16 + chunk
  int b = blk >> 4, chunk = blk & 15;
  // zero-init pooled slice (runs before k_fused's atomicMax)
  for (int i = tid; i < 2048; i += 256) pooled[blk * 2048 + i] = 0u;
  if (tid < 192) cls[tid] = csum[b * 192 + tid];
  __syncthreads();
  if (tid < 64) {
    int m = tid;
    float s0 = cls[m*3], s1 = cls[m*3+1], c = cls[m*3+2];
    float mx = s0 / (c + 1e-5f), my = s1 / (c + 1e-5f);
    rowflag[b*64 + m] = (c > 0.f) ? 1 : 0;         // redundant identical writes, safe
    for (int r = 0; r < 4; ++r) {
      float th = 1.5707964f * (float)r;
      float cr = cosf(th), sr = sinf(th);
      noderot[((b*4+r)*2+0)*64 + m] = cr*mx - sr*my;
      noderot[((b*4+r)*2+1)*64 + m] = sr*mx + cr*my;
    }
    lc[m] = 0;
  }
  if (tid == 0) {                 // serial prefix over 64 m (counts exact in fp32)
    int acc = 0;
    for (int mm = 0; mm < 64; ++mm) { offs[mm] = acc; acc += (int)cls[mm*3+2]; }
  }
  __syncthreads();
  if (tid < 64) {
    int base = offs[tid];
    for (int c2 = 0; c2 < chunk; ++c2) base += blkcnt[(b*16 + c2)*64 + tid];
    lbase[tid] = base;
  }
  __syncthreads();
  int n = (chunk << 8) + tid;
#pragma unroll
  for (int kk = 0; kk < 3; ++kk) {
    int m = idx[((long)b*NN + n)*3 + kk];
    int pos = atomicAdd(&lc[m], 1);               // LDS atomic, order irrelevant
    sorted[b*KNN + lbase[m] + pos] = (m << 12) | n;
  }
}

// ---------------- K3: fused fp block (xdec -> 4 layers -> run-scan segment max) ------
// grid (192, 16): 64 m-sorted columns per block, one br per blockIdx.y.
__global__ __launch_bounds__(256) void k_fused(
    const void* __restrict__ x, const int* __restrict__ sorted,
    const int* __restrict__ idx, const float* __restrict__ noderot,
    const unsigned short* __restrict__ Wb,
    unsigned int* __restrict__ pooled, float* __restrict__ feat0) {
  __shared__ unsigned short Cs[64 * 136];   // [col][0..1]=xdec,[2..129]=h2; later [0..127]=feat
  __shared__ unsigned short Hs[64 * 72];    // h1 (stride 72 -> 144B, 16B-mult)
  __shared__ int mcol[64];                  // m | (is_col0 << 8)
  const unsigned short* fW1 = Wb + W_FPW1;
  const unsigned short* fW2 = Wb + W_FPW2;
  const unsigned short* fW3 = Wb + W_FPW3;
  const unsigned short* fb1 = Wb + W_FPB1;
  const unsigned short* fb2 = Wb + W_FPB2;
  const unsigned short* fb3 = Wb + W_FPB3;
  const unsigned short* fb0 = Wb + W_FPB0;
  const unsigned short* fW0 = Wb + W_FPW0;
  int isbf = detect_bf((const unsigned short*)x);
  int tid = threadIdx.x, lane = tid & 63, wv = tid >> 6;
  int quad = lane >> 4, lr = lane & 15;
  int br = blockIdx.y, b = br >> 2, r = br & 3;
  if (tid < 64) {
    int e = sorted[b * KNN + blockIdx.x * 64 + tid];
    int m = e >> 12, n = e & 4095;
    int isz = (n == 0 && m == idx[(long)b * NN * 3]) ? 256 : 0;
    mcol[tid] = m | isz;
    float x0 = ldf(x, b*8192 + n, isbf), x1 = ldf(x, b*8192 + 4096 + n, isbf);
    float th = 1.5707964f * (float)r;
    float cr = cosf(th), sr = sinf(th);
    float xd0 = (cr*x0 - sr*x1) - noderot[(br*2 + 0)*64 + m];
    float xd1 = (sr*x0 + cr*x1) - noderot[(br*2 + 1)*64 + m];
    *(unsigned int*)&Cs[tid * 136] = f2bf2(xd0, xd1);
  }
  __syncthreads();
  // ----- layer0 (2 -> 64), VALU -----
  {
    int col = tid & 63, og = (tid >> 6) << 4;
    unsigned int xu = *(unsigned int*)&Cs[col * 136];
    float fx0 = bf2f(xu & 0xffff), fx1 = bf2f(xu >> 16);
    union { unsigned int u[8]; bf16x8 v[2]; } o8;
#pragma unroll
    for (int j = 0; j < 16; j += 2) {
      int o = og + j;
      unsigned int wu0 = *(const unsigned int*)&fW0[o*2];
      unsigned int wu1 = *(const unsigned int*)&fW0[o*2 + 2];
      float h0 = bf2f(fb0[o])   + bf2f(wu0 & 0xffff)*fx0 + bf2f(wu0 >> 16)*fx1;
      float h1 = bf2f(fb0[o+1]) + bf2f(wu1 & 0xffff)*fx0 + bf2f(wu1 >> 16)*fx1;
      o8.u[j >> 1] = f2bf2(fmaxf(h0, 0.f), fmaxf(h1, 0.f));
    }
    *(bf16x8*)&Hs[col*72 + og]     = o8.v[0];
    *(bf16x8*)&Hs[col*72 + og + 8] = o8.v[1];
  }
  __syncthreads();
  // ----- layer1 (64 -> 64), MFMA -----
  {
    int o0 = wv * 16;
    f32x4 acc[4];
    float bb4[4];
#pragma unroll
    for (int rr = 0; rr < 4; ++rr) bb4[rr] = bf2f(fb1[o0 + quad*4 + rr]);
#pragma unroll
    for (int nt = 0; nt < 4; ++nt) acc[nt] = (f32x4){bb4[0], bb4[1], bb4[2], bb4[3]};
#pragma unroll
    for (int ks = 0; ks < 64; ks += 32) {
      bf16x8 a = *(const bf16x8*)(fW1 + (o0 + lr)*64 + ks + quad*8);
#pragma unroll
      for (int nt = 0; nt < 4; ++nt) {
        bf16x8 bf = *(bf16x8*)&Hs[(nt*16 + lr)*72 + ks + quad*8];
        acc[nt] = __builtin_amdgcn_mfma_f32_16x16x32_bf16(a, bf, acc[nt], 0, 0, 0);
      }
    }
    __syncthreads();  // everyone done READING Hs
#pragma unroll
    for (int nt = 0; nt < 4; ++nt) {
      int col = nt*16 + lr;
      unsigned long long pk =
        (unsigned long long)f2bf2(fmaxf(acc[nt][0],0.f), fmaxf(acc[nt][1],0.f)) |
        ((unsigned long long)f2bf2(fmaxf(acc[nt][2],0.f), fmaxf(acc[nt][3],0.f)) << 32);
      *(unsigned long long*)&Hs[col*72 + o0 + quad*4] = pk;
    }
  }
  __syncthreads();
  // ----- layer2 (64 -> 128), MFMA, output into Cs[2..129] -----
#pragma unroll
  for (int p2 = 0; p2 < 2; ++p2) {
    int o0 = p2*64 + wv*16;
    f32x4 acc[4];
    float bb4[4];
#pragma unroll
    for (int rr = 0; rr < 4; ++rr) bb4[rr] = bf2f(fb2[o0 + quad*4 + rr]);
#pragma unroll
    for (int nt = 0; nt < 4; ++nt) acc[nt] = (f32x4){bb4[0], bb4[1], bb4[2], bb4[3]};
#pragma unroll
    for (int ks = 0; ks < 64; ks += 32) {
      bf16x8 a = *(const bf16x8*)(fW2 + (o0 + lr)*64 + ks + quad*8);
#pragma unroll
      for (int nt = 0; nt < 4; ++nt) {
        bf16x8 bf = *(bf16x8*)&Hs[(nt*16 + lr)*72 + ks + quad*8];
        acc[nt] = __builtin_amdgcn_mfma_f32_16x16x32_bf16(a, bf, acc[nt], 0, 0, 0);
      }
    }
#pragma unroll
    for (int nt = 0; nt < 4; ++nt) {
      int col = nt*16 + lr;
      int o = o0 + quad*4;
      *(unsigned int*)&Cs[col*136 + 2 + o] = f2bf2(fmaxf(acc[nt][0],0.f), fmaxf(acc[nt][1],0.f));
      *(unsigned int*)&Cs[col*136 + 4 + o] = f2bf2(fmaxf(acc[nt][2],0.f), fmaxf(acc[nt][3],0.f));
    }
  }
  __syncthreads();
  // ----- layer3 (130 -> 128): both halves in registers, then feats -> Cs[0..127] -----
  f32x4 acc3[2][4];
#pragma unroll
  for (int p3 = 0; p3 < 2; ++p3) {
    int o0 = p3*64 + wv*16;
    float bb4[4];
#pragma unroll
    for (int rr = 0; rr < 4; ++rr) bb4[rr] = bf2f(fb3[o0 + quad*4 + rr]);
#pragma unroll
    for (int nt = 0; nt < 4; ++nt) acc3[p3][nt] = (f32x4){bb4[0], bb4[1], bb4[2], bb4[3]};
#pragma unroll
    for (int ks = 0; ks < 128; ks += 32) {
      union { bf16x8 v; unsigned int u[4]; } au;
      const unsigned int* ap = (const unsigned int*)(fW3 + (long)(o0 + lr)*130 + ks + quad*8);
      au.u[0] = ap[0]; au.u[1] = ap[1]; au.u[2] = ap[2]; au.u[3] = ap[3];
#pragma unroll
      for (int nt = 0; nt < 4; ++nt) {
        bf16x8 bf = *(bf16x8*)&Cs[(nt*16 + lr)*136 + ks + quad*8];
        acc3[p3][nt] = __builtin_amdgcn_mfma_f32_16x16x32_bf16(au.v, bf, acc3[p3][nt], 0, 0, 0);
      }
    }
#pragma unroll
    for (int rr = 0; rr < 4; ++rr) {   // K tail: channels 128..129
      int o = o0 + quad*4 + rr;
      unsigned int wu = *(const unsigned int*)(fW3 + (long)o*130 + 128);
      float w0 = bf2f(wu & 0xffff), w1 = bf2f(wu >> 16);
#pragma unroll
      for (int nt = 0; nt < 4; ++nt) {
        unsigned int bu = *(unsigned int*)&Cs[(nt*16 + lr)*136 + 128];
        acc3[p3][nt][rr] += w0 * bf2f(bu & 0xffff) + w1 * bf2f(bu >> 16);
      }
    }
  }
  __syncthreads();   // ALL Cs reads complete before feat overwrite
#pragma unroll
  for (int p3 = 0; p3 < 2; ++p3) {
    int o0 = p3*64 + wv*16;
#pragma unroll
    for (int nt = 0; nt < 4; ++nt) {
      int col = nt*16 + lr;
      unsigned long long pk =
        (unsigned long long)f2bf2(fmaxf(acc3[p3][nt][0],0.f), fmaxf(acc3[p3][nt][1],0.f)) |
        ((unsigned long long)f2bf2(fmaxf(acc3[p3][nt][2],0.f), fmaxf(acc3[p3][nt][3],0.f)) << 32);
      *(unsigned long long*)&Cs[col*136 + o0 + quad*4] = pk;
    }
  }
  __syncthreads();
  // ----- run-scan segment max: gather 32 values into registers (ILP), then scan -----
  {
    int o = tid & 127, h = tid >> 7;
    int c0 = h * 32;
    float fv[32];
#pragma unroll
    for (int j = 0; j < 32; ++j) fv[j] = bf2f(Cs[(c0 + j)*136 + o]);
    int curm = mcol[c0] & 255;
    float v = 0.f;                       // relu'd values >= 0
#pragma unroll
    for (int j = 0; j < 32; ++j) {
      int mc = mcol[c0 + j];
      int mm = mc & 255;
      if (mm != curm) {
        atomicMax(&pooled[(((long)br*64 + curm) << 7) + o], __float_as_uint(v));
        curm = mm; v = 0.f;
      }
      v = fmaxf(v, fv[j]);
      if (mc & 256) feat0[br*128 + o] = fv[j];   // (kk=0,n=0) column
    }
    atomicMax(&pooled[(((long)br*64 + curm) << 7) + o], __float_as_uint(v));
  }
}

// ---------------- K4: fused gp block, 1024 threads (16 waves) per block --------------
// grid 64: 16 columns (one br, 16 m's) per block, whole gp chain in LDS.
__global__ __launch_bounds__(1024) void k_gp(
    const void* __restrict__ x,
    const unsigned int* __restrict__ pooled, const float* __restrict__ feat0,
    const int* __restrict__ rowflag, const float* __restrict__ noderot,
    const unsigned short* __restrict__ Wb,
    unsigned int* __restrict__ outmax, unsigned int* __restrict__ counter,
    void* __restrict__ out) {
  __shared__ unsigned short AGs[16 * 648];  // [col][0..1]=node,[2..129]=pooled,[130..641]=h2
  __shared__ unsigned short H1s[16 * 264];
  __shared__ unsigned short H2s[16 * 264];
  __shared__ int done_s;
  int isbf = detect_bf((const unsigned short*)x);
  int tid = threadIdx.x, lane = tid & 63, wv = tid >> 6;   // wv 0..15
  int quad = lane >> 4, lr = lane & 15;
  int col0 = blockIdx.x * 16;
  int br = col0 >> 6, b = br >> 2;
  // ---- stage A: build AG tile (finalize) ----
  for (int i = tid; i < 2048; i += 1024) {
    int c = i >> 7, o = i & 127;
    int gc = col0 + c, m = gc & 63;
    float v = __uint_as_float(pooled[((long)gc << 7) + o]);
    if (!rowflag[b * 64 + m]) v = feat0[br * 128 + o];
    AGs[c * 648 + 2 + o] = f2bf(v);
  }
  if (tid < 32) {
    int c = tid >> 1, j = tid & 1;
    int m = (col0 + c) & 63;
    AGs[c * 648 + j] = f2bf(noderot[(br * 2 + j) * 64 + m]);
  }
  __syncthreads();
  // ---- gp0: 256 rows (1 tile/wave), K=130 (128 MFMA + 2 tail) ----
  {
    const unsigned short* W = Wb + W_GPW0;
    const unsigned short* Bi = Wb + W_GPB0;
    int o0 = wv * 16;
    f32x4 acc;
    {
      int ob = o0 + quad*4;
      acc = (f32x4){bf2f(Bi[ob]), bf2f(Bi[ob+1]), bf2f(Bi[ob+2]), bf2f(Bi[ob+3])};
    }
#pragma unroll
    for (int ks = 0; ks < 128; ks += 32) {
      bf16x8 bfr = *(bf16x8*)&AGs[lr * 648 + ks + quad * 8];
      union { bf16x8 v; unsigned int u[4]; } au;
      const unsigned int* ap = (const unsigned int*)(W + (o0 + lr)*130 + ks + quad*8);
      au.u[0]=ap[0]; au.u[1]=ap[1]; au.u[2]=ap[2]; au.u[3]=ap[3];
      acc = __builtin_amdgcn_mfma_f32_16x16x32_bf16(au.v, bfr, acc, 0,0,0);
    }
    unsigned int bu = *(unsigned int*)&AGs[lr * 648 + 128];
    float b0v = bf2f(bu & 0xffff), b1v = bf2f(bu >> 16);
#pragma unroll
    for (int rr = 0; rr < 4; ++rr) {
      int o = o0 + quad*4 + rr;
      unsigned int wu = *(const unsigned int*)(W + o*130 + 128);
      acc[rr] += bf2f(wu & 0xffff)*b0v + bf2f(wu >> 16)*b1v;
    }
    unsigned long long pk =
      (unsigned long long)f2bf2(fmaxf(acc[0],0.f), fmaxf(acc[1],0.f)) |
      ((unsigned long long)f2bf2(fmaxf(acc[2],0.f), fmaxf(acc[3],0.f)) << 32);
    *(unsigned long long*)&H1s[lr*264 + o0 + quad*4] = pk;
  }
  __syncthreads();
  // ---- gp1: 256 rows (1 tile/wave), K=256 ----
  {
    const unsigned short* W = Wb + W_GPW1;
    const unsigned short* Bi = Wb + W_GPB1;
    int o0 = wv * 16;
    f32x4 acc;
    {
      int ob = o0 + quad*4;
      acc = (f32x4){bf2f(Bi[ob]), bf2f(Bi[ob+1]), bf2f(Bi[ob+2]), bf2f(Bi[ob+3])};
    }
#pragma unroll
    for (int ks = 0; ks < 256; ks += 32) {
      bf16x8 bfr = *(bf16x8*)&H1s[lr * 264 + ks + quad * 8];
      bf16x8 a = *(const bf16x8*)(W + (o0 + lr)*256 + ks + quad*8);
      acc = __builtin_amdgcn_mfma_f32_16x16x32_bf16(a, bfr, acc, 0,0,0);
    }
    unsigned long long pk =
      (unsigned long long)f2bf2(fmaxf(acc[0],0.f), fmaxf(acc[1],0.f)) |
      ((unsigned long long)f2bf2(fmaxf(acc[2],0.f), fmaxf(acc[3],0.f)) << 32);
    *(unsigned long long*)&H2s[lr*264 + o0 + quad*4] = pk;
  }
  __syncthreads();
  // ---- gp2: 512 rows (2 tiles/wave), K=256, out -> AGs[130..641] ----
  {
    const unsigned short* W = Wb + W_GPW2;
    const unsigned short* Bi = Wb + W_GPB2;
    f32x4 acc[2];
#pragma unroll
    for (int rt = 0; rt < 2; ++rt) {
      int ob = wv*32 + rt*16 + quad*4;
      acc[rt] = (f32x4){bf2f(Bi[ob]), bf2f(Bi[ob+1]), bf2f(Bi[ob+2]), bf2f(Bi[ob+3])};
    }
#pragma unroll
    for (int ks = 0; ks < 256; ks += 32) {
      bf16x8 bfr = *(bf16x8*)&H2s[lr * 264 + ks + quad * 8];
#pragma unroll
      for (int rt = 0; rt < 2; ++rt) {
        int o0 = wv*32 + rt*16;
        bf16x8 a = *(const bf16x8*)(W + (o0 + lr)*256 + ks + quad*8);
        acc[rt] = __builtin_amdgcn_mfma_f32_16x16x32_bf16(a, bfr, acc[rt], 0,0,0);
      }
    }
#pragma unroll
    for (int rt = 0; rt < 2; ++rt) {
      int o0 = wv*32 + rt*16;
      *(unsigned int*)&AGs[lr*648 + 130 + o0 + quad*4] =
          f2bf2(fmaxf(acc[rt][0],0.f), fmaxf(acc[rt][1],0.f));
      *(unsigned int*)&AGs[lr*648 + 132 + o0 + quad*4] =
          f2bf2(fmaxf(acc[rt][2],0.f), fmaxf(acc[rt][3],0.f));
    }
  }
  __syncthreads();
  // ---- gp3: 512 rows (2 tiles/wave), K=642 (640 MFMA + 2 tail), relu+max -> outmax --
  {
    const unsigned short* W = Wb + W_GPW3;
    const unsigned short* Bi = Wb + W_GPB3;
    f32x4 acc[2];
#pragma unroll
    for (int rt = 0; rt < 2; ++rt) {
      int ob = wv*32 + rt*16 + quad*4;
      acc[rt] = (f32x4){bf2f(Bi[ob]), bf2f(Bi[ob+1]), bf2f(Bi[ob+2]), bf2f(Bi[ob+3])};
    }
    for (int ks = 0; ks < 640; ks += 32) {
      bf16x8 bfr = *(bf16x8*)&AGs[lr * 648 + ks + quad * 8];
#pragma unroll
      for (int rt = 0; rt < 2; ++rt) {
        int o0 = wv*32 + rt*16;
        union { bf16x8 v; unsigned int u[4]; } au;
        const unsigned int* ap = (const unsigned int*)(W + (long)(o0 + lr)*642 + ks + quad*8);
        au.u[0]=ap[0]; au.u[1]=ap[1]; au.u[2]=ap[2]; au.u[3]=ap[3];
        acc[rt] = __builtin_amdgcn_mfma_f32_16x16x32_bf16(au.v, bfr, acc[rt], 0,0,0);
      }
    }
    unsigned int bu = *(unsigned int*)&AGs[lr * 648 + 640];
    float b0v = bf2f(bu & 0xffff), b1v = bf2f(bu >> 16);
#pragma unroll
    for (int rt = 0; rt < 2; ++rt) {
#pragma unroll
      for (int rr = 0; rr < 4; ++rr) {
        int o = wv*32 + rt*16 + quad*4 + rr;
        unsigned int wu = *(const unsigned int*)(W + (long)o*642 + 640);
        float v = acc[rt][rr] + bf2f(wu & 0xffff)*b0v + bf2f(wu >> 16)*b1v;
        v = fmaxf(v, 0.f);
        v = fmaxf(v, __shfl_xor(v, 1, 64));
        v = fmaxf(v, __shfl_xor(v, 2, 64));
        v = fmaxf(v, __shfl_xor(v, 4, 64));
        v = fmaxf(v, __shfl_xor(v, 8, 64));
        if (lr == 0) atomicMax(&outmax[b * FF + o], __float_as_uint(v));
      }
    }
  }
  // ---- last block converts outmax -> out ----
  __threadfence();
  __syncthreads();
  if (tid == 0) done_s = (int)atomicAdd(counter, 1u);
  __syncthreads();
  if (done_s == 63) {
    for (int t = tid; t < 2048; t += 1024) {
      float v = __uint_as_float(atomicMax(&outmax[t], 0u));  // coherent device-scope read
      if (isbf) ((unsigned short*)out)[t] = f2bf(v);
      else      ((float*)out)[t] = v;
    }
  }
}

// ---------------- host ----------------
extern "C" void kernel_launch(void* const* d_in, const int* in_sizes, int n_in,
                              void* d_out, int out_size, void* d_ws, size_t ws_size,
                              hipStream_t stream) {
  const void* x    = d_in[0];
  const void* node = d_in[2];

  char* ws = (char*)d_ws;
  float*          csum    = (float*)(ws + 0);              //   3072
  unsigned int*   outmax  = (unsigned int*)(ws + 3072);    //   8192
  unsigned int*   counter = (unsigned int*)(ws + 11264);   //    256
  // ---- end of memset region (11520 B) ----
  unsigned int*   pooled  = (unsigned int*)(ws + 11520);   // 524288 (zeroed by k_mid)
  int*            idx     = (int*)(ws + 535808);           // 196608
  int*            blkcnt  = (int*)(ws + 732416);           //  16384
  float*          noderot = (float*)(ws + 748800);         //   8192
  int*            rowflag = (int*)(ws + 756992);           //   1024
  int*            sorted  = (int*)(ws + 758016);           // 196608
  float*          feat0   = (float*)(ws + 954624);         //   8192
  unsigned short* Wb      = (unsigned short*)(ws + 962816);// 1179136 -> end 2141952

  hipMemsetAsync(ws, 0, 11520, stream);

  SrcPtrs sp;
  sp.p[0]  = d_in[6];   // fpW1
  sp.p[1]  = d_in[8];   // fpW2
  sp.p[2]  = d_in[10];  // fpW3
  sp.p[3]  = d_in[12];  // gpW0
  sp.p[4]  = d_in[14];  // gpW1
  sp.p[5]  = d_in[16];  // gpW2
  sp.p[6]  = d_in[18];  // gpW3
  sp.p[7]  = d_in[7];   // fpb1
  sp.p[8]  = d_in[9];   // fpb2
  sp.p[9]  = d_in[11];  // fpb3
  sp.p[10] = d_in[13];  // gpb0
  sp.p[11] = d_in[15];  // gpb1
  sp.p[12] = d_in[17];  // gpb2
  sp.p[13] = d_in[19];  // gpb3
  sp.p[14] = d_in[5];   // fpb0
  sp.p[15] = d_in[4];   // fpW0

  k_pre<<<64 + (W_TOT + 255) / 256, 256, 0, stream>>>(sp, x, node, idx, csum, blkcnt, Wb);
  k_mid<<<64, 256, 0, stream>>>(csum, blkcnt, idx, noderot, rowflag, sorted, pooled);
  k_fused<<<dim3(192, 16), 256, 0, stream>>>(x, sorted, idx, noderot, Wb, pooled, feat0);
  k_gp<<<64, 1024, 0, stream>>>(x, pooled, feat0, rowflag, noderot, Wb,
                                outmax, counter, d_out);
}

// Round 7
// 203.573 us; speedup vs baseline: 1.2043x; 1.0111x over previous
//
#include <hip/hip_runtime.h>
#include <stdint.h>

// ---------------- problem constants ----------------
#define BB 4
#define RR 4
#define NN 4096
#define MM 64
#define KK 3
#define KNN 12288           // KK*NN
#define BRR 16              // BB*RR
#define FF 512

// canonical bf16 weight arena offsets (elements)
#define W_FPW1 0
#define W_FPW2 4096
#define W_FPW3 12288
#define W_GPW0 28928
#define W_GPW1 62208
#define W_GPW2 127744
#define W_GPW3 258816
#define W_FPB1 587520
#define W_FPB2 587584
#define W_FPB3 587712
#define W_GPB0 587840
#define W_GPB1 588096
#define W_GPB2 588352
#define W_GPB3 588864
#define W_FPB0 589376
#define W_FPW0 589440
#define W_TOT  589568

typedef short bf16x8 __attribute__((ext_vector_type(8)));
typedef float f32x4 __attribute__((ext_vector_type(4)));

__device__ __forceinline__ float bf2f(unsigned int u) {
  union { unsigned int i; float f; } v; v.i = u << 16; return v.f;
}
__device__ __forceinline__ unsigned short f2bf(float f) {
  union { float f; unsigned int i; } v; v.f = f;
  unsigned int x = v.i;
  return (unsigned short)((x + 0x7fffu + ((x >> 16) & 1u)) >> 16);
}
__device__ __forceinline__ unsigned int f2bf2(float a, float b) {
#if __has_builtin(__builtin_amdgcn_cvt_pk_bf16_f32)
  typedef __bf16 bf2_t __attribute__((ext_vector_type(2)));
  union { bf2_t v; unsigned int u; } c;
  c.v = __builtin_amdgcn_cvt_pk_bf16_f32(a, b);
  return c.u;
#else
  return (unsigned int)f2bf(a) | ((unsigned int)f2bf(b) << 16);
#endif
}
__device__ __forceinline__ float ldf(const void* p, long i, int isbf) {
  if (isbf) return bf2f(((const unsigned short*)p)[i]);
  return ((const float*)p)[i];
}
// per-wave dtype probe: sample 64 even-index ushorts of x, vote on exponents
__device__ __forceinline__ int detect_bf(const unsigned short* xs) {
  int lane = threadIdx.x & 63;
  unsigned short u = xs[lane * 2];
  int e = (u >> 7) & 0xFF;
  int bad = (e >= 0x90 || (e > 0 && e <= 0x50)) ? 1 : 0;
  unsigned long long m = __ballot(bad);
  return __popcll(m) < 16;
}

// ---------------- K1: weight canonicalize (blocks >=64, 2 elems/thread) + assign ----
struct SrcPtrs { const void* p[16]; };
__global__ __launch_bounds__(256) void k_pre(
    SrcPtrs sp, const void* __restrict__ x, const void* __restrict__ node,
    int* __restrict__ idx, float* __restrict__ csum, int* __restrict__ blkcnt,
    unsigned short* __restrict__ Wb) {
  int isbf = detect_bf((const unsigned short*)x);
  int tid = threadIdx.x;
  if (blockIdx.x >= 64) {
    int t2 = (blockIdx.x - 64) * 256 + tid;   // pair index
    int t = t2 * 2;
    if (t >= W_TOT) return;
    int s, base;
    if (t < 28928) {
      if (t < 4096)        { s=0;  base=0; }
      else if (t < 12288)  { s=1;  base=4096; }
      else                 { s=2;  base=12288; }
    } else if (t < 587520) {
      if (t < 62208)       { s=3;  base=28928; }
      else if (t < 127744) { s=4;  base=62208; }
      else if (t < 258816) { s=5;  base=127744; }
      else                 { s=6;  base=258816; }
    } else if (t < 588864) {
      if (t < 587584)      { s=7;  base=587520; }
      else if (t < 587712) { s=8;  base=587584; }
      else if (t < 587840) { s=9;  base=587712; }
      else if (t < 588096) { s=10; base=587840; }
      else if (t < 588352) { s=11; base=588096; }
      else                 { s=12; base=588352; }
    } else {
      if (t < 589376)      { s=13; base=588864; }
      else if (t < 589440) { s=14; base=589376; }
      else                 { s=15; base=589440; }
    }
    int local = t - base;                      // even (all bases even)
    unsigned int pk;
    if (isbf) pk = *(const unsigned int*)((const unsigned short*)sp.p[s] + local);
    else {
      const float* fp = (const float*)sp.p[s] + local;
      pk = f2bf2(fp[0], fp[1]);
    }
    *(unsigned int*)(Wb + t) = pk;
    return;
  }
  // ---- assign part ----
  __shared__ float nd[2][64];
  __shared__ float cs[192];
  int b = blockIdx.x >> 4;
  int n = ((blockIdx.x & 15) << 8) + tid;
  if (tid < 128) nd[tid >> 6][tid & 63] = ldf(node, b * 128 + tid, isbf);
  if (tid < 192) cs[tid] = 0.f;
  __syncthreads();
  float x0 = ldf(x, b * 8192 + n, isbf);
  float x1 = ldf(x, b * 8192 + 4096 + n, isbf);
  float d0 = 1e30f, d1 = 1e30f, d2 = 1e30f;
  int m0 = 0, m1 = 0, m2 = 0;
#pragma unroll 8
  for (int m = 0; m < 64; ++m) {
    float dx = x0 - nd[0][m];
    float dy = x1 - nd[1][m];
    float d = __fmul_rn(dx, dx) + __fmul_rn(dy, dy);
    if (d < d0)      { d2=d1; m2=m1; d1=d0; m1=m0; d0=d; m0=m; }
    else if (d < d1) { d2=d1; m2=m1; d1=d;  m1=m; }
    else if (d < d2) { d2=d;  m2=m; }
  }
  long base = ((long)b * NN + n) * 3;
  idx[base] = m0; idx[base + 1] = m1; idx[base + 2] = m2;
  atomicAdd(&cs[m0*3+0], x0); atomicAdd(&cs[m0*3+1], x1); atomicAdd(&cs[m0*3+2], 1.f);
  atomicAdd(&cs[m1*3+0], x0); atomicAdd(&cs[m1*3+1], x1); atomicAdd(&cs[m1*3+2], 1.f);
  atomicAdd(&cs[m2*3+0], x0); atomicAdd(&cs[m2*3+1], x1); atomicAdd(&cs[m2*3+2], 1.f);
  __syncthreads();
  if (tid < 192) atomicAdd(&csum[b * 192 + tid], cs[tid]);
  if (tid < 64) blkcnt[blockIdx.x * 64 + tid] = (int)cs[tid*3 + 2];
}

// ---------------- K2: means + prefix + counting-sort scatter + pooled init ----------
__global__ __launch_bounds__(256) void k_mid(
    const float* __restrict__ csum, const int* __restrict__ blkcnt,
    const int* __restrict__ idx,
    float* __restrict__ noderot, int* __restrict__ rowflag,
    int* __restrict__ sorted, unsigned int* __restrict__ pooled) {
  __shared__ float cls[192];
  __shared__ int offs[64];
  __shared__ int lbase[64];
  __shared__ int lc[64];
  int tid = threadIdx.x;
  int blk = blockIdx.x;           // b*16 + chunk
  int b = blk >> 4, chunk = blk & 15;
  for (int i = tid; i < 2048; i += 256) pooled[blk * 2048 + i] = 0u;
  if (tid < 192) cls[tid] = csum[b * 192 + tid];
  __syncthreads();
  if (tid < 64) {
    int m = tid;
    float s0 = cls[m*3], s1 = cls[m*3+1], c = cls[m*3+2];
    float mx = s0 / (c + 1e-5f), my = s1 / (c + 1e-5f);
    rowflag[b*64 + m] = (c > 0.f) ? 1 : 0;
    for (int r = 0; r < 4; ++r) {
      float th = 1.5707964f * (float)r;
      float cr = cosf(th), sr = sinf(th);
      noderot[((b*4+r)*2+0)*64 + m] = cr*mx - sr*my;
      noderot[((b*4+r)*2+1)*64 + m] = sr*mx + cr*my;
    }
    lc[m] = 0;
  }
  if (tid == 0) {
    int acc = 0;
    for (int mm = 0; mm < 64; ++mm) { offs[mm] = acc; acc += (int)cls[mm*3+2]; }
  }
  __syncthreads();
  if (tid < 64) {
    int base = offs[tid];
    for (int c2 = 0; c2 < chunk; ++c2) base += blkcnt[(b*16 + c2)*64 + tid];
    lbase[tid] = base;
  }
  __syncthreads();
  int n = (chunk << 8) + tid;
#pragma unroll
  for (int kk = 0; kk < 3; ++kk) {
    int m = idx[((long)b*NN + n)*3 + kk];
    int pos = atomicAdd(&lc[m], 1);
    sorted[b*KNN + lbase[m] + pos] = (m << 12) | n;
  }
}

// ---------------- K3: fused fp block, 512 thr / 128 cols per block -------------------
// grid (96, 16): 128 m-sorted columns per block, one br per blockIdx.y.
__global__ __launch_bounds__(512, 6) void k_fused(
    const void* __restrict__ x, const int* __restrict__ sorted,
    const int* __restrict__ idx, const float* __restrict__ noderot,
    const unsigned short* __restrict__ Wb,
    unsigned int* __restrict__ pooled, float* __restrict__ feat0) {
  __shared__ unsigned short Cs[128 * 136];  // [col][0..1]=xdec,[2..129]=h2; later [0..127]=feat
  __shared__ unsigned short Hs[128 * 72];   // h1 (stride 72 -> 144B)
  __shared__ int mcol[128];                 // m | (is_col0 << 8)
  const unsigned short* fW1 = Wb + W_FPW1;
  const unsigned short* fW2 = Wb + W_FPW2;
  const unsigned short* fW3 = Wb + W_FPW3;
  const unsigned short* fb1 = Wb + W_FPB1;
  const unsigned short* fb2 = Wb + W_FPB2;
  const unsigned short* fb3 = Wb + W_FPB3;
  const unsigned short* fb0 = Wb + W_FPB0;
  const unsigned short* fW0 = Wb + W_FPW0;
  int isbf = detect_bf((const unsigned short*)x);
  int tid = threadIdx.x, lane = tid & 63, wv = tid >> 6;   // wv 0..7
  int quad = lane >> 4, lr = lane & 15;
  int br = blockIdx.y, b = br >> 2, r = br & 3;
  if (tid < 128) {
    int e = sorted[b * KNN + blockIdx.x * 128 + tid];
    int m = e >> 12, n = e & 4095;
    int isz = (n == 0 && m == idx[(long)b * NN * 3]) ? 256 : 0;
    mcol[tid] = m | isz;
    float x0 = ldf(x, b*8192 + n, isbf), x1 = ldf(x, b*8192 + 4096 + n, isbf);
    float th = 1.5707964f * (float)r;
    float cr = cosf(th), sr = sinf(th);
    float xd0 = (cr*x0 - sr*x1) - noderot[(br*2 + 0)*64 + m];
    float xd1 = (sr*x0 + cr*x1) - noderot[(br*2 + 1)*64 + m];
    *(unsigned int*)&Cs[tid * 136] = f2bf2(xd0, xd1);
  }
  __syncthreads();
  // ----- layer0 (2 -> 64), VALU: col=tid&127, rows og..og+15 -----
  {
    int col = tid & 127, og = (tid >> 7) << 4;   // 0,16,32,48
    unsigned int xu = *(unsigned int*)&Cs[col * 136];
    float fx0 = bf2f(xu & 0xffff), fx1 = bf2f(xu >> 16);
    union { unsigned int u[8]; bf16x8 v[2]; } o8;
#pragma unroll
    for (int j = 0; j < 16; j += 2) {
      int o = og + j;
      unsigned int wu0 = *(const unsigned int*)&fW0[o*2];
      unsigned int wu1 = *(const unsigned int*)&fW0[o*2 + 2];
      float h0 = bf2f(fb0[o])   + bf2f(wu0 & 0xffff)*fx0 + bf2f(wu0 >> 16)*fx1;
      float h1 = bf2f(fb0[o+1]) + bf2f(wu1 & 0xffff)*fx0 + bf2f(wu1 >> 16)*fx1;
      o8.u[j >> 1] = f2bf2(fmaxf(h0, 0.f), fmaxf(h1, 0.f));
    }
    *(bf16x8*)&Hs[col*72 + og]     = o8.v[0];
    *(bf16x8*)&Hs[col*72 + og + 8] = o8.v[1];
  }
  __syncthreads();
  // ----- layer1 (64 -> 64): wave = rows (wv&3)*16 x cols (wv>>2)*64 -----
  {
    int o0 = (wv & 3) * 16, cb = (wv >> 2) * 64;
    f32x4 acc[4];
    float bb4[4];
#pragma unroll
    for (int rr = 0; rr < 4; ++rr) bb4[rr] = bf2f(fb1[o0 + quad*4 + rr]);
#pragma unroll
    for (int nt = 0; nt < 4; ++nt) acc[nt] = (f32x4){bb4[0], bb4[1], bb4[2], bb4[3]};
#pragma unroll
    for (int ks = 0; ks < 64; ks += 32) {
      bf16x8 a = *(const bf16x8*)(fW1 + (o0 + lr)*64 + ks + quad*8);
#pragma unroll
      for (int nt = 0; nt < 4; ++nt) {
        bf16x8 bf = *(bf16x8*)&Hs[(cb + nt*16 + lr)*72 + ks + quad*8];
        acc[nt] = __builtin_amdgcn_mfma_f32_16x16x32_bf16(a, bf, acc[nt], 0, 0, 0);
      }
    }
    __syncthreads();  // all Hs reads done
#pragma unroll
    for (int nt = 0; nt < 4; ++nt) {
      int col = cb + nt*16 + lr;
      unsigned long long pk =
        (unsigned long long)f2bf2(fmaxf(acc[nt][0],0.f), fmaxf(acc[nt][1],0.f)) |
        ((unsigned long long)f2bf2(fmaxf(acc[nt][2],0.f), fmaxf(acc[nt][3],0.f)) << 32);
      *(unsigned long long*)&Hs[col*72 + o0 + quad*4] = pk;
    }
  }
  __syncthreads();
  // ----- layer2 (64 -> 128): wave = rows wv*16 x all 128 cols -----
  {
    int o0 = wv * 16;
    f32x4 acc[8];
    float bb4[4];
#pragma unroll
    for (int rr = 0; rr < 4; ++rr) bb4[rr] = bf2f(fb2[o0 + quad*4 + rr]);
#pragma unroll
    for (int nt = 0; nt < 8; ++nt) acc[nt] = (f32x4){bb4[0], bb4[1], bb4[2], bb4[3]};
#pragma unroll
    for (int ks = 0; ks < 64; ks += 32) {
      bf16x8 a = *(const bf16x8*)(fW2 + (o0 + lr)*64 + ks + quad*8);
#pragma unroll
      for (int nt = 0; nt < 8; ++nt) {
        bf16x8 bf = *(bf16x8*)&Hs[(nt*16 + lr)*72 + ks + quad*8];
        acc[nt] = __builtin_amdgcn_mfma_f32_16x16x32_bf16(a, bf, acc[nt], 0, 0, 0);
      }
    }
#pragma unroll
    for (int nt = 0; nt < 8; ++nt) {  // write into Cs[2..129] (disjoint from Hs)
      int col = nt*16 + lr;
      int o = o0 + quad*4;
      *(unsigned int*)&Cs[col*136 + 2 + o] = f2bf2(fmaxf(acc[nt][0],0.f), fmaxf(acc[nt][1],0.f));
      *(unsigned int*)&Cs[col*136 + 4 + o] = f2bf2(fmaxf(acc[nt][2],0.f), fmaxf(acc[nt][3],0.f));
    }
  }
  __syncthreads();
  // ----- layer3 (130 -> 128): wave = rows wv*16 x all 128 cols -----
  f32x4 acc3[8];
  {
    int o0 = wv * 16;
    float bb4[4];
#pragma unroll
    for (int rr = 0; rr < 4; ++rr) bb4[rr] = bf2f(fb3[o0 + quad*4 + rr]);
#pragma unroll
    for (int nt = 0; nt < 8; ++nt) acc3[nt] = (f32x4){bb4[0], bb4[1], bb4[2], bb4[3]};
#pragma unroll
    for (int ks = 0; ks < 128; ks += 32) {
      union { bf16x8 v; unsigned int u[4]; } au;
      const unsigned int* ap = (const unsigned int*)(fW3 + (long)(o0 + lr)*130 + ks + quad*8);
      au.u[0] = ap[0]; au.u[1] = ap[1]; au.u[2] = ap[2]; au.u[3] = ap[3];
#pragma unroll
      for (int nt = 0; nt < 8; ++nt) {
        bf16x8 bf = *(bf16x8*)&Cs[(nt*16 + lr)*136 + ks + quad*8];
        acc3[nt] = __builtin_amdgcn_mfma_f32_16x16x32_bf16(au.v, bf, acc3[nt], 0, 0, 0);
      }
    }
#pragma unroll
    for (int rr = 0; rr < 4; ++rr) {   // K tail: channels 128..129
      int o = o0 + quad*4 + rr;
      unsigned int wu = *(const unsigned int*)(fW3 + (long)o*130 + 128);
      float w0 = bf2f(wu & 0xffff), w1 = bf2f(wu >> 16);
#pragma unroll
      for (int nt = 0; nt < 8; ++nt) {
        unsigned int bu = *(unsigned int*)&Cs[(nt*16 + lr)*136 + 128];
        acc3[nt][rr] += w0 * bf2f(bu & 0xffff) + w1 * bf2f(bu >> 16);
      }
    }
  }
  __syncthreads();   // ALL Cs reads complete before feat overwrite
  {
    int o0 = wv * 16;
#pragma unroll
    for (int nt = 0; nt < 8; ++nt) {
      int col = nt*16 + lr;
      unsigned long long pk =
        (unsigned long long)f2bf2(fmaxf(acc3[nt][0],0.f), fmaxf(acc3[nt][1],0.f)) |
        ((unsigned long long)f2bf2(fmaxf(acc3[nt][2],0.f), fmaxf(acc3[nt][3],0.f)) << 32);
      *(unsigned long long*)&Cs[col*136 + o0 + quad*4] = pk;
    }
  }
  __syncthreads();
  // ----- run-scan segment max: thread = (row o, chunk h of 32 cols) -----
  {
    int o = tid & 127, h = tid >> 7;   // h 0..3
    int c0 = h * 32;
    float fv[32];
#pragma unroll
    for (int j = 0; j < 32; ++j) fv[j] = bf2f(Cs[(c0 + j)*136 + o]);
    int curm = mcol[c0] & 255;
    float v = 0.f;
#pragma unroll
    for (int j = 0; j < 32; ++j) {
      int mc = mcol[c0 + j];
      int mm = mc & 255;
      if (mm != curm) {
        atomicMax(&pooled[(((long)br*64 + curm) << 7) + o], __float_as_uint(v));
        curm = mm; v = 0.f;
      }
      v = fmaxf(v, fv[j]);
      if (mc & 256) feat0[br*128 + o] = fv[j];
    }
    atomicMax(&pooled[(((long)br*64 + curm) << 7) + o], __float_as_uint(v));
  }
}

// ---------------- K4: finalize -> AG[1024][648] cols 0..129 -------------------------
__global__ __launch_bounds__(256) void k_fin(
    const unsigned int* __restrict__ pooled, const float* __restrict__ feat0,
    const int* __restrict__ rowflag, const float* __restrict__ noderot,
    unsigned short* __restrict__ AG) {
  int t = blockIdx.x * 256 + threadIdx.x;  // 131072
  int col = t >> 7, o = t & 127;
  int br = col >> 6, m = col & 63, b = br >> 2;
  float v = __uint_as_float(pooled[((long)col << 7) + o]);
  if (!rowflag[b*64 + m]) v = feat0[br*128 + o];
  AG[(long)col*648 + 2 + o] = f2bf(v);
  if (o < 2) AG[(long)col*648 + o] = f2bf(noderot[(br*2 + o)*64 + m]);
}

// ---------------- gp GEMM: grid (64 col-tiles, R/16/... row-blocks of 64) ------------
// wave = 16 rows x 16 cols. Out[col*OSTR + OOFF + o] = relu(bias + W.B)
// EPI 0: bf16 store; EPI 2: relu + max over 16 cols -> atomicMax outmax; counter-out.
template<int KW, int KMAIN, bool REM2, int BSTR, int OSTR, int OOFF, int EPI, bool AAL, int TOTB>
__global__ __launch_bounds__(256) void k_gemm2(
    const unsigned short* __restrict__ W, const unsigned short* __restrict__ Bi,
    const unsigned short* __restrict__ Bb, unsigned short* __restrict__ Out,
    unsigned int* __restrict__ outmax, unsigned int* __restrict__ counter,
    const void* __restrict__ x, void* __restrict__ out) {
  __shared__ int done_s;
  int lane = threadIdx.x & 63, wv = threadIdx.x >> 6;
  int quad = lane >> 4, lr = lane & 15;
  int o0 = blockIdx.y * 64 + wv * 16;
  int p0 = blockIdx.x * 16;
  f32x4 acc;
  {
    int ob = o0 + quad*4;
    acc = (f32x4){bf2f(Bi[ob]), bf2f(Bi[ob+1]), bf2f(Bi[ob+2]), bf2f(Bi[ob+3])};
  }
  const unsigned short* arow = W + (long)(o0 + lr) * KW;
  const unsigned short* brow = Bb + (long)(p0 + lr) * BSTR;
#pragma unroll 4
  for (int ks = 0; ks < KMAIN; ks += 32) {
    bf16x8 a;
    if constexpr (AAL) {
      a = *(const bf16x8*)(arow + ks + quad*8);
    } else {
      union { bf16x8 v; unsigned int u[4]; } au;
      const unsigned int* ap = (const unsigned int*)(arow + ks + quad*8);
      au.u[0] = ap[0]; au.u[1] = ap[1]; au.u[2] = ap[2]; au.u[3] = ap[3];
      a = au.v;
    }
    bf16x8 bf = *(const bf16x8*)(brow + ks + quad*8);
    acc = __builtin_amdgcn_mfma_f32_16x16x32_bf16(a, bf, acc, 0, 0, 0);
  }
  if constexpr (REM2) {
    unsigned int bu = *(const unsigned int*)(brow + KMAIN);
    float b0v = bf2f(bu & 0xffff), b1v = bf2f(bu >> 16);
#pragma unroll
    for (int rr = 0; rr < 4; ++rr) {
      int o = o0 + quad*4 + rr;
      unsigned int wu = *(const unsigned int*)(W + (long)o * KW + KMAIN);
      acc[rr] += bf2f(wu & 0xffff) * b0v + bf2f(wu >> 16) * b1v;
    }
  }
  if constexpr (EPI == 0) {
    unsigned short* op = Out + (long)(p0 + lr) * OSTR + OOFF + o0 + quad*4;
    if constexpr (((OOFF * 2) % 8) == 0) {
      unsigned long long pk =
        (unsigned long long)f2bf2(fmaxf(acc[0],0.f), fmaxf(acc[1],0.f)) |
        ((unsigned long long)f2bf2(fmaxf(acc[2],0.f), fmaxf(acc[3],0.f)) << 32);
      *(unsigned long long*)op = pk;
    } else {
      *(unsigned int*)op       = f2bf2(fmaxf(acc[0],0.f), fmaxf(acc[1],0.f));
      *(unsigned int*)(op + 2) = f2bf2(fmaxf(acc[2],0.f), fmaxf(acc[3],0.f));
    }
  } else {  // EPI == 2: 16 cols all in one br -> b = blockIdx.x>>4
    int b = blockIdx.x >> 4;
#pragma unroll
    for (int rr = 0; rr < 4; ++rr) {
      float v = fmaxf(acc[rr], 0.f);
      v = fmaxf(v, __shfl_xor(v, 1, 64));
      v = fmaxf(v, __shfl_xor(v, 2, 64));
      v = fmaxf(v, __shfl_xor(v, 4, 64));
      v = fmaxf(v, __shfl_xor(v, 8, 64));
      if (lr == 0) atomicMax(&outmax[b * FF + o0 + quad*4 + rr], __float_as_uint(v));
    }
    __threadfence();
    __syncthreads();
    if (threadIdx.x == 0) done_s = (int)atomicAdd(counter, 1u);
    __syncthreads();
    if (done_s == TOTB - 1) {
      int isbf = detect_bf((const unsigned short*)x);
      for (int t = threadIdx.x; t < 2048; t += 256) {
        float v = __uint_as_float(atomicMax(&outmax[t], 0u));
        if (isbf) ((unsigned short*)out)[t] = f2bf(v);
        else      ((float*)out)[t] = v;
      }
    }
  }
}

// ---------------- host ----------------
extern "C" void kernel_launch(void* const* d_in, const int* in_sizes, int n_in,
                              void* d_out, int out_size, void* d_ws, size_t ws_size,
                              hipStream_t stream) {
  const void* x    = d_in[0];
  const void* node = d_in[2];

  char* ws = (char*)d_ws;
  float*          csum    = (float*)(ws + 0);              //   3072
  unsigned int*   outmax  = (unsigned int*)(ws + 3072);    //   8192
  unsigned int*   counter = (unsigned int*)(ws + 11264);   //    256
  // ---- end of memset region (11520 B) ----
  unsigned int*   pooled  = (unsigned int*)(ws + 11520);   // 524288 (zeroed by k_mid)
  int*            idx     = (int*)(ws + 535808);           // 196608
  int*            blkcnt  = (int*)(ws + 732416);           //  16384
  float*          noderot = (float*)(ws + 748800);         //   8192
  int*            rowflag = (int*)(ws + 756992);           //   1024
  int*            sorted  = (int*)(ws + 758016);           // 196608
  float*          feat0   = (float*)(ws + 954624);         //   8192
  unsigned short* Wb      = (unsigned short*)(ws + 962816);// 1179136 -> 2141952
  unsigned short* AG      = (unsigned short*)(ws + 2141952);  // 1327104 -> 3469056
  unsigned short* Hg1     = (unsigned short*)(ws + 3469056);  // 524288 -> 3993344
  unsigned short* Hg2     = (unsigned short*)(ws + 3993344);  // 524288 -> 4517632

  hipMemsetAsync(ws, 0, 11520, stream);

  SrcPtrs sp;
  sp.p[0]  = d_in[6];   // fpW1
  sp.p[1]  = d_in[8];   // fpW2
  sp.p[2]  = d_in[10];  // fpW3
  sp.p[3]  = d_in[12];  // gpW0
  sp.p[4]  = d_in[14];  // gpW1
  sp.p[5]  = d_in[16];  // gpW2
  sp.p[6]  = d_in[18];  // gpW3
  sp.p[7]  = d_in[7];   // fpb1
  sp.p[8]  = d_in[9];   // fpb2
  sp.p[9]  = d_in[11];  // fpb3
  sp.p[10] = d_in[13];  // gpb0
  sp.p[11] = d_in[15];  // gpb1
  sp.p[12] = d_in[17];  // gpb2
  sp.p[13] = d_in[19];  // gpb3
  sp.p[14] = d_in[5];   // fpb0
  sp.p[15] = d_in[4];   // fpW0

  k_pre<<<64 + (W_TOT/2 + 255) / 256, 256, 0, stream>>>(sp, x, node, idx, csum, blkcnt, Wb);
  k_mid<<<64, 256, 0, stream>>>(csum, blkcnt, idx, noderot, rowflag, sorted, pooled);
  k_fused<<<dim3(96, 16), 512, 0, stream>>>(x, sorted, idx, noderot, Wb, pooled, feat0);
  k_fin<<<512, 256, 0, stream>>>(pooled, feat0, rowflag, noderot, AG);

  // gp layers, row-split: wave = 16x16 tile
  k_gemm2<130, 128, true, 648, 256, 0, 0, false, 0>
      <<<dim3(64, 4), 256, 0, stream>>>(Wb + W_GPW0, Wb + W_GPB0, AG, Hg1,
                                        nullptr, nullptr, x, nullptr);
  k_gemm2<256, 256, false, 256, 256, 0, 0, true, 0>
      <<<dim3(64, 4), 256, 0, stream>>>(Wb + W_GPW1, Wb + W_GPB1, Hg1, Hg2,
                                        nullptr, nullptr, x, nullptr);
  k_gemm2<256, 256, false, 256, 648, 130, 0, true, 0>
      <<<dim3(64, 8), 256, 0, stream>>>(Wb + W_GPW2, Wb + W_GPB2, Hg2, AG,
                                        nullptr, nullptr, x, nullptr);
  k_gemm2<642, 640, true, 648, 0, 0, 2, false, 512>
      <<<dim3(64, 8), 256, 0, stream>>>(Wb + W_GPW3, Wb + W_GPB3, AG, nullptr,
                                        outmax, counter, x, d_out);
}